// Round 2
// baseline (377.231 us; speedup 1.0000x reference)
//
#include <hip/hip_runtime.h>

// Involution: out[b, g*64+c, ho, wo] = sum_{kh,kw} xp[b, g*64+c, ho+kh, wo+kw] * W[b,g,kh,kw,ho,wo]
// B=8, C=512, G=8, cpg=64, H=W=Ho=Wo=64, K=7, PAD=3. fp32.
//
// R2 changes vs R1:
//  - channel split 4x: each block does 16 channels -> 2048 blocks (8/CU) for latency hiding.
//  - __launch_bounds__(256,4): VGPR cap 128 so the 98 weight VGPRs stay RESIDENT
//    (R1 compiled to 64 VGPRs -> weights re-fetched every channel = the 188us).
//  - LDS row stride 71 (odd): float2 window reads hit all 32 banks evenly
//    (R1 stride 70 caused 2x phase conflicts, 9.4M conflict cycles).

#define BB 8
#define CC 512
#define GG 8
#define CPG 64
#define HH 64
#define WW 64
#define KK 7
#define PAD 3

#define TILE_ROWS 8                      // output rows per block
#define CSPLIT 4
#define CH_PER_BLOCK (CPG / CSPLIT)      // 16
#define LDS_ROWS (TILE_ROWS + KK - 1)    // 14
#define LDS_COLS (WW + KK - 1)           // 70 (valid data)
#define LDS_PITCH 71                     // odd pitch -> conflict-free float2 reads
#define LDS_REAL (LDS_ROWS * LDS_COLS)   // 980 elements to fill

__global__ __launch_bounds__(256, 4)
void involution_kernel(const float* __restrict__ x,
                       const float* __restrict__ weight,
                       float* __restrict__ out) {
    const int tid = threadIdx.x;
    const int tx = tid & 31;          // 0..31 -> wo0 = 2*tx
    const int ty = tid >> 5;          // 0..7  -> row within tile
    const int bx = blockIdx.x;        // 0..31: tile = bx>>2, cs = bx&3
    const int tile = bx >> 2;
    const int cs = bx & 3;
    const int g = blockIdx.y;         // 0..7
    const int b = blockIdx.z;         // 0..7

    const int wo0 = tx << 1;          // even
    const int hbase = tile * TILE_ROWS;
    const int ho = hbase + ty;

    __shared__ float xs[LDS_ROWS * LDS_PITCH];

    // ---- preload the 49 per-pixel weights as float2 (covers wo0, wo0+1) ----
    const float* wp = weight + ((b * GG + g) * (KK * KK)) * (HH * WW)
                             + ho * WW + wo0;
    float2 w[KK * KK];
#pragma unroll
    for (int t = 0; t < KK * KK; ++t) {
        w[t] = *(const float2*)(wp + t * (HH * WW));
    }

    const int c0 = cs * CH_PER_BLOCK;
    const float* xg = x + ((b * CC + g * CPG + c0) * (HH * WW));
    float* og = out + ((b * CC + g * CPG + c0) * (HH * WW)) + ho * WW + wo0;

#pragma unroll 1
    for (int c = 0; c < CH_PER_BLOCK; ++c) {
        // ---- stage padded x plane rows [hbase-3 .. hbase+10], cols [-3..66] ----
        const float* xc = xg + c * (HH * WW);
#pragma unroll 1
        for (int i = tid; i < LDS_REAL; i += 256) {
            const int r = i / LDS_COLS;          // const divisor -> magic mul
            const int s = i - r * LDS_COLS;
            const int xr = hbase + r - PAD;
            const int xcol = s - PAD;
            float v = 0.0f;
            if (xr >= 0 && xr < HH && xcol >= 0 && xcol < WW)
                v = xc[xr * WW + xcol];
            xs[r * LDS_PITCH + s] = v;
        }
        __syncthreads();

        // ---- compute 2 outputs ----
        float acc0 = 0.0f, acc1 = 0.0f;
#pragma unroll
        for (int kh = 0; kh < KK; ++kh) {
            const float* row = &xs[(ty + kh) * LDS_PITCH + wo0];
            const float2 p0 = *(const float2*)(row + 0);
            const float2 p1 = *(const float2*)(row + 2);
            const float2 p2 = *(const float2*)(row + 4);
            const float2 p3 = *(const float2*)(row + 6);
            const float f0 = p0.x, f1 = p0.y, f2 = p1.x, f3 = p1.y;
            const float f4 = p2.x, f5 = p2.y, f6 = p3.x, f7 = p3.y;
            const float2 w0 = w[kh * KK + 0];
            const float2 w1 = w[kh * KK + 1];
            const float2 w2 = w[kh * KK + 2];
            const float2 w3 = w[kh * KK + 3];
            const float2 w4 = w[kh * KK + 4];
            const float2 w5 = w[kh * KK + 5];
            const float2 w6 = w[kh * KK + 6];
            acc0 = fmaf(f0, w0.x, acc0);  acc1 = fmaf(f1, w0.y, acc1);
            acc0 = fmaf(f1, w1.x, acc0);  acc1 = fmaf(f2, w1.y, acc1);
            acc0 = fmaf(f2, w2.x, acc0);  acc1 = fmaf(f3, w2.y, acc1);
            acc0 = fmaf(f3, w3.x, acc0);  acc1 = fmaf(f4, w3.y, acc1);
            acc0 = fmaf(f4, w4.x, acc0);  acc1 = fmaf(f5, w4.y, acc1);
            acc0 = fmaf(f5, w5.x, acc0);  acc1 = fmaf(f6, w5.y, acc1);
            acc0 = fmaf(f6, w6.x, acc0);  acc1 = fmaf(f7, w6.y, acc1);
        }

        float2 o; o.x = acc0; o.y = acc1;
        *(float2*)(og + c * (HH * WW)) = o;

        __syncthreads();   // protect xs before next channel's staging
    }
}

extern "C" void kernel_launch(void* const* d_in, const int* in_sizes, int n_in,
                              void* d_out, int out_size, void* d_ws, size_t ws_size,
                              hipStream_t stream) {
    const float* x = (const float*)d_in[0];
    const float* w = (const float*)d_in[1];
    float* out = (float*)d_out;

    dim3 grid((HH / TILE_ROWS) * CSPLIT, GG, BB);   // (32, 8, 8) = 2048 blocks
    dim3 block(256);
    involution_kernel<<<grid, block, 0, stream>>>(x, w, out);
}

// Round 3
// 223.785 us; speedup vs baseline: 1.6857x; 1.6857x over previous
//
#include <hip/hip_runtime.h>

// Involution: out[b, g*64+c, ho, wo] = sum_{kh,kw} xp[b, g*64+c, ho+kh, wo+kw] * W[b,g,kh,kw,ho,wo]
// B=8, C=512, G=8, cpg=64, H=W=Ho=Wo=64, K=7, PAD=3. fp32.
//
// R3 changes vs R2:
//  - WEIGHTS PINNED IN REGISTERS via volatile loads. R1/R2 compiled to 64 VGPRs:
//    the compiler rematerialized the 49 weight loads inside the channel loop
//    (~3.3 GB of L2 traffic, latency-bound at 8-12% VALUBusy). Volatile accesses
//    cannot be duplicated -> the 98 values must stay live. Cap 256 VGPR (256,2).
//  - CSPLIT=2 (was 4): weight over-fetch only 2x, grid 1024.
//  - Quad-aligned staging: stage x cols [-4,68) so each float4 staging load is
//    fully in-bounds or fully out -> one predicated dwordx4 per thread.
//  - LDS pitch 72, x col c stored at lds col c+4; window = 5 aligned b64/row.
//  - Software-pipelined staging: load channel c+1 while computing channel c.

#define BB 8
#define CC 512
#define GG 8
#define CPG 64
#define HH 64
#define WW 64
#define KK 7
#define PAD 3

#define TILE_ROWS 8
#define CSPLIT 2
#define NCH (CPG / CSPLIT)              // 32 channels per block
#define LDS_ROWS (TILE_ROWS + KK - 1)   // 14
#define LDS_PITCH 72                    // words/row; x col c -> lds col c+4
#define NQUADS (LDS_ROWS * (LDS_PITCH / 4))  // 252 float4 stage slots

__global__ __launch_bounds__(256, 2)
void involution_kernel(const float* __restrict__ x,
                       const float* __restrict__ weight,
                       float* __restrict__ out) {
    const int tid = threadIdx.x;
    const int tx = tid & 31;          // 0..31 -> wo0 = 2*tx
    const int ty = tid >> 5;          // 0..7  -> row within tile
    const int bx = blockIdx.x;        // 0..15
    const int tile = bx >> 1;
    const int cs = bx & 1;
    const int g = blockIdx.y;
    const int b = blockIdx.z;

    const int wo0 = tx << 1;
    const int hbase = tile * TILE_ROWS;
    const int ho = hbase + ty;

    __shared__ float xs[LDS_ROWS * LDS_PITCH];   // 4032 B

    // ---- 49 per-pixel weight pairs, pinned via volatile (non-duplicable) ----
    const volatile float* wp = weight
        + ((size_t)(b * GG + g) * (KK * KK)) * (HH * WW) + ho * WW + wo0;
    float w0[KK * KK], w1[KK * KK];
#pragma unroll
    for (int t = 0; t < KK * KK; ++t) {
        w0[t] = wp[t * (HH * WW)];
        w1[t] = wp[t * (HH * WW) + 1];
    }

    // ---- staging geometry (fixed per thread) ----
    const int sr = tid / 18;              // 0..13 (tid < 252)
    const int sq = tid - sr * 18;         // 0..17
    const int xrow = hbase + sr - PAD;    // row in x
    const int xcol = sq * 4 - 4;          // quad start col: -4..64
    const bool sval = (tid < NQUADS)
                   && ((unsigned)xrow < HH) && ((unsigned)xcol < WW);
    const int soff = xrow * WW + xcol;
    float* lds_dst = &xs[sr * LDS_PITCH + sq * 4];

    const size_t cbase = (size_t)(b * CC + g * CPG + cs * NCH) * (HH * WW);
    const float* xg = x + cbase;
    float* og = out + cbase + ho * WW + wo0;

    // ---- software-pipelined channel loop ----
    float4 stg = make_float4(0.f, 0.f, 0.f, 0.f);
    if (sval) stg = *(const float4*)(xg + soff);

#pragma unroll 1
    for (int c = 0; c < NCH; ++c) {
        __syncthreads();                       // xs free from previous compute
        if (tid < NQUADS) *(float4*)lds_dst = stg;
        __syncthreads();                       // tile visible

        if (c + 1 < NCH) {                     // issue next tile early
            float4 nx = make_float4(0.f, 0.f, 0.f, 0.f);
            if (sval) nx = *(const float4*)(xg + (size_t)(c + 1) * (HH * WW) + soff);
            stg = nx;
        }

        float acc0 = 0.f, acc1 = 0.f;
#pragma unroll
        for (int kh = 0; kh < KK; ++kh) {
            const float* row = &xs[(ty + kh) * LDS_PITCH + wo0];
            const float2 p0 = *(const float2*)(row + 0);
            const float2 p1 = *(const float2*)(row + 2);
            const float2 p2 = *(const float2*)(row + 4);
            const float2 p3 = *(const float2*)(row + 6);
            const float2 p4 = *(const float2*)(row + 8);
            const float f0 = p0.x, f1 = p0.y, f2 = p1.x, f3 = p1.y, f4 = p2.x;
            const float f5 = p2.y, f6 = p3.x, f7 = p3.y, f8 = p4.x;
            // f[i] = x col (wo0 - 4 + i); pixel wo0 tap kw -> f[kw+1], pixel wo0+1 -> f[kw+2]
            acc0 = fmaf(f1, w0[kh * 7 + 0], acc0);  acc1 = fmaf(f2, w1[kh * 7 + 0], acc1);
            acc0 = fmaf(f2, w0[kh * 7 + 1], acc0);  acc1 = fmaf(f3, w1[kh * 7 + 1], acc1);
            acc0 = fmaf(f3, w0[kh * 7 + 2], acc0);  acc1 = fmaf(f4, w1[kh * 7 + 2], acc1);
            acc0 = fmaf(f4, w0[kh * 7 + 3], acc0);  acc1 = fmaf(f5, w1[kh * 7 + 3], acc1);
            acc0 = fmaf(f5, w0[kh * 7 + 4], acc0);  acc1 = fmaf(f6, w1[kh * 7 + 4], acc1);
            acc0 = fmaf(f6, w0[kh * 7 + 5], acc0);  acc1 = fmaf(f7, w1[kh * 7 + 5], acc1);
            acc0 = fmaf(f7, w0[kh * 7 + 6], acc0);  acc1 = fmaf(f8, w1[kh * 7 + 6], acc1);
        }

        *(float2*)(og + (size_t)c * (HH * WW)) = make_float2(acc0, acc1);
    }
}

extern "C" void kernel_launch(void* const* d_in, const int* in_sizes, int n_in,
                              void* d_out, int out_size, void* d_ws, size_t ws_size,
                              hipStream_t stream) {
    const float* x = (const float*)d_in[0];
    const float* w = (const float*)d_in[1];
    float* out = (float*)d_out;

    dim3 grid((HH / TILE_ROWS) * CSPLIT, GG, BB);   // (16, 8, 8) = 1024 blocks
    dim3 block(256);
    involution_kernel<<<grid, block, 0, stream>>>(x, w, out);
}

// Round 4
// 201.641 us; speedup vs baseline: 1.8708x; 1.1098x over previous
//
#include <hip/hip_runtime.h>

// Involution: out[b, g*64+c, ho, wo] = sum_{kh,kw} xp[b, g*64+c, ho+kh, wo+kw] * W[b,g,kh,kw,ho,wo]
// B=8, C=512, G=8, cpg=64, H=W=Ho=Wo=64, K=7, PAD=3. fp32.
//
// R4: registers lost R1-R3 (compiler pins at 64 VGPR, spills 98 weights to
// scratch -> per-channel scratch-reload latency wall, VALUBusy 13%).
// Restructure so live weight state is tiny:
//   - channels processed in chunks of 8; 8 channel x-planes staged in LDS
//     at once (8 x 14 x 72 x 4B = 32 KB).
//   - loop kh OUTER, ch INNER: only 7 float2 weights (14 VGPRs) live at a
//     time, re-loaded per chunk from global (L2-resident, ~12us hidden).
//   - accumulators 8 ch x 2 px = 16 VGPRs. Peak live ~90 -> no spill.
//   - CSPLIT=2 -> 1024 blocks, 4 blocks/CU, 16 waves/CU.

#define BB 8
#define CC 512
#define GG 8
#define CPG 64
#define HH 64
#define WW 64
#define HW (HH * WW)
#define KK 7
#define PAD 3

#define TILE_ROWS 8
#define CSPLIT 2
#define NCHUNK 4                         // channel chunks per block
#define CHPC 8                           // channels per chunk
#define LDS_ROWS (TILE_ROWS + KK - 1)    // 14
#define LDS_PITCH 72                     // x col c -> lds col c+4
#define CH_STRIDE (LDS_ROWS * LDS_PITCH) // 1008 words per channel plane
#define NQUADS (LDS_ROWS * (LDS_PITCH / 4))  // 252 quad slots per plane

__global__ __launch_bounds__(256, 4)
void involution_kernel(const float* __restrict__ x,
                       const float* __restrict__ weight,
                       float* __restrict__ out) {
    const int tid = threadIdx.x;
    const int tx = tid & 31;          // wo0 = 2*tx
    const int ty = tid >> 5;          // row within tile
    const int bx = blockIdx.x;        // 0..15
    const int tile = bx >> 1;
    const int cs = bx & 1;
    const int g = blockIdx.y;
    const int b = blockIdx.z;

    const int wo0 = tx << 1;
    const int hbase = tile * TILE_ROWS;
    const int ho = hbase + ty;

    __shared__ float xs[CHPC * CH_STRIDE];   // 32256 B

    // per-pixel weight base: taps at +t*HW, float2 covers wo0,wo0+1
    const float* wq = weight + ((size_t)(b * GG + g) * (KK * KK)) * HW
                    + ho * WW + wo0;

    // staging geometry
    const int sr = tid / 18;              // 0..13 (tid < 252)
    const int sq = tid - sr * 18;         // 0..17
    const int xrow = hbase + sr - PAD;
    const int xcol = sq * 4 - 4;          // -4..64, quad aligned
    const bool sval = (tid < NQUADS)
                   && ((unsigned)xrow < HH) && ((unsigned)xcol < WW);
    const int soff = xrow * WW + xcol;
    const int ldsoff = sr * LDS_PITCH + sq * 4;

    const size_t cbase = (size_t)(b * CC + g * CPG + cs * (NCHUNK * CHPC)) * HW;
    const float* xg = x + cbase;
    float* og = out + cbase + ho * WW + wo0;

#pragma unroll 1
    for (int cc = 0; cc < NCHUNK; ++cc) {
        // ---- stage 8 channel planes ----
        float4 q[CHPC];
#pragma unroll
        for (int ch = 0; ch < CHPC; ++ch) {
            float4 v = make_float4(0.f, 0.f, 0.f, 0.f);
            if (sval)
                v = *(const float4*)(xg + (size_t)(cc * CHPC + ch) * HW + soff);
            q[ch] = v;
        }
        __syncthreads();                 // previous chunk's readers done
        if (tid < NQUADS) {
#pragma unroll
            for (int ch = 0; ch < CHPC; ++ch)
                *(float4*)(&xs[ch * CH_STRIDE + ldsoff]) = q[ch];
        }
        __syncthreads();                 // planes visible

        // ---- compute: kh outer (7 float2 weights live), ch inner ----
        float acc0[CHPC], acc1[CHPC];
#pragma unroll
        for (int ch = 0; ch < CHPC; ++ch) { acc0[ch] = 0.f; acc1[ch] = 0.f; }

#pragma unroll
        for (int kh = 0; kh < KK; ++kh) {
            float2 wk[KK];
#pragma unroll
            for (int j = 0; j < KK; ++j)
                wk[j] = *(const float2*)(wq + (size_t)(kh * KK + j) * HW);

#pragma unroll
            for (int ch = 0; ch < CHPC; ++ch) {
                const float* row = &xs[ch * CH_STRIDE + (ty + kh) * LDS_PITCH + wo0];
                const float2 p0 = *(const float2*)(row + 0);
                const float2 p1 = *(const float2*)(row + 2);
                const float2 p2 = *(const float2*)(row + 4);
                const float2 p3 = *(const float2*)(row + 6);
                const float2 p4 = *(const float2*)(row + 8);
                const float f1 = p0.y, f2 = p1.x, f3 = p1.y, f4 = p2.x;
                const float f5 = p2.y, f6 = p3.x, f7 = p3.y, f8 = p4.x;
                float a0 = acc0[ch], a1 = acc1[ch];
                a0 = fmaf(f1, wk[0].x, a0);  a1 = fmaf(f2, wk[0].y, a1);
                a0 = fmaf(f2, wk[1].x, a0);  a1 = fmaf(f3, wk[1].y, a1);
                a0 = fmaf(f3, wk[2].x, a0);  a1 = fmaf(f4, wk[2].y, a1);
                a0 = fmaf(f4, wk[3].x, a0);  a1 = fmaf(f5, wk[3].y, a1);
                a0 = fmaf(f5, wk[4].x, a0);  a1 = fmaf(f6, wk[4].y, a1);
                a0 = fmaf(f6, wk[5].x, a0);  a1 = fmaf(f7, wk[5].y, a1);
                a0 = fmaf(f7, wk[6].x, a0);  a1 = fmaf(f8, wk[6].y, a1);
                acc0[ch] = a0; acc1[ch] = a1;
            }
        }

        // ---- store 8 channels x 2 pixels ----
#pragma unroll
        for (int ch = 0; ch < CHPC; ++ch) {
            *(float2*)(og + (size_t)(cc * CHPC + ch) * HW)
                = make_float2(acc0[ch], acc1[ch]);
        }
    }
}

extern "C" void kernel_launch(void* const* d_in, const int* in_sizes, int n_in,
                              void* d_out, int out_size, void* d_ws, size_t ws_size,
                              hipStream_t stream) {
    const float* x = (const float*)d_in[0];
    const float* w = (const float*)d_in[1];
    float* out = (float*)d_out;

    dim3 grid((HH / TILE_ROWS) * CSPLIT, GG, BB);   // (16, 8, 8) = 1024 blocks
    dim3 block(256);
    involution_kernel<<<grid, block, 0, stream>>>(x, w, out);
}